// Round 1
// baseline (1073.212 us; speedup 1.0000x reference)
//
#include <hip/hip_runtime.h>
#include <math.h>

// ---------------------------------------------------------------------------
// Fused GAT(4 heads, 32 ch) + GCN + gated fusion + residual + LayerNorm
// N=50000 nodes, D=128, E=800000 edges (+ N self-loops handled analytically)
// ---------------------------------------------------------------------------

// K1: fused GEMM  h = x @ gat_W (128x128), g = x @ gcn_W (128x128)
// Block: 256 threads, tile = 32 rows x 256 cols (cols 0-127 -> h, 128-255 -> g)
__global__ __launch_bounds__(256) void k_gemm(
    const float* __restrict__ x, const float* __restrict__ Wg,
    const float* __restrict__ Wc, float* __restrict__ hfeat,
    float* __restrict__ gfeat, int n)
{
    __shared__ float xs[32][128];
    const int row0 = blockIdx.x * 32;
    const int t = threadIdx.x;

    #pragma unroll
    for (int i = 0; i < 16; ++i) {
        int idx = t + i * 256;
        int r = idx >> 7, c = idx & 127;
        int gr = row0 + r;
        xs[r][c] = (gr < n) ? x[(size_t)gr * 128 + c] : 0.f;
    }
    __syncthreads();

    float acc[32];
    #pragma unroll
    for (int r = 0; r < 32; ++r) acc[r] = 0.f;

    const float* Wp = (t < 128) ? (Wg + t) : (Wc + (t - 128));
    for (int k0 = 0; k0 < 128; k0 += 4) {
        float w0 = Wp[(k0 + 0) * 128];
        float w1 = Wp[(k0 + 1) * 128];
        float w2 = Wp[(k0 + 2) * 128];
        float w3 = Wp[(k0 + 3) * 128];
        #pragma unroll
        for (int r = 0; r < 32; ++r) {
            const float4 xv = *reinterpret_cast<const float4*>(&xs[r][k0]);
            acc[r] = fmaf(xv.x, w0, fmaf(xv.y, w1, fmaf(xv.z, w2, fmaf(xv.w, w3, acc[r]))));
        }
    }

    float* outp = (t < 128) ? (hfeat + t) : (gfeat + (t - 128));
    #pragma unroll
    for (int r = 0; r < 32; ++r) {
        int gr = row0 + r;
        if (gr < n) outp[(size_t)gr * 128] = acc[r];
    }
}

// K2: per-node attention logits a_src[n,h], a_dst[n,h]  (wave per node)
__global__ __launch_bounds__(256) void k_att(
    const float* __restrict__ hfeat, const float* __restrict__ att_src,
    const float* __restrict__ att_dst, float* __restrict__ a_src,
    float* __restrict__ a_dst, int n)
{
    const int wave = threadIdx.x >> 6;
    const int lane = threadIdx.x & 63;
    const int node = blockIdx.x * 4 + wave;
    if (node >= n) return;
    float h0 = hfeat[(size_t)node * 128 + lane];
    float h1 = hfeat[(size_t)node * 128 + lane + 64];
    float s0 = h0 * att_src[lane], s1 = h1 * att_src[lane + 64];
    float d0 = h0 * att_dst[lane], d1 = h1 * att_dst[lane + 64];
    #pragma unroll
    for (int off = 16; off >= 1; off >>= 1) {
        s0 += __shfl_xor(s0, off);
        s1 += __shfl_xor(s1, off);
        d0 += __shfl_xor(d0, off);
        d1 += __shfl_xor(d1, off);
    }
    if ((lane & 31) == 0) {
        int g = lane >> 5;  // 0 or 1 -> heads {0,1}; +2 for upper channels
        a_src[node * 4 + g]     = s0;
        a_src[node * 4 + 2 + g] = s1;
        a_dst[node * 4 + g]     = d0;
        a_dst[node * 4 + 2 + g] = d1;
    }
}

// K3: node init: deg = 1 (self-loop), w_sum = exp(leaky(e_self))
__global__ void k_nodeinit(const float* __restrict__ a_src,
                           const float* __restrict__ a_dst,
                           float* __restrict__ deg, float* __restrict__ wsum, int n)
{
    int i = blockIdx.x * blockDim.x + threadIdx.x;
    if (i >= n) return;
    deg[i] = 1.0f;
    #pragma unroll
    for (int h = 0; h < 4; ++h) {
        float e = a_src[i * 4 + h] + a_dst[i * 4 + h];
        e = e > 0.f ? e : 0.2f * e;
        wsum[i * 4 + h] = expf(e);
    }
}

// K4: degree accumulation over real edges
__global__ void k_deg(const int* __restrict__ dst, float* __restrict__ deg, int E)
{
    int i = blockIdx.x * blockDim.x + threadIdx.x;
    if (i >= E) return;
    unsafeAtomicAdd(&deg[dst[i]], 1.0f);
}

// K5: softmax denominator accumulation over real edges
__global__ void k_wsum(const int* __restrict__ src, const int* __restrict__ dst,
                       const float* __restrict__ a_src, const float* __restrict__ a_dst,
                       float* __restrict__ wsum, int E)
{
    int i = blockIdx.x * blockDim.x + threadIdx.x;
    if (i >= E) return;
    int s = src[i], d = dst[i];
    const float4 as = *reinterpret_cast<const float4*>(a_src + (size_t)s * 4);
    const float4 ad = *reinterpret_cast<const float4*>(a_dst + (size_t)d * 4);
    float e;
    e = as.x + ad.x; e = e > 0.f ? e : 0.2f * e; unsafeAtomicAdd(&wsum[d * 4 + 0], expf(e));
    e = as.y + ad.y; e = e > 0.f ? e : 0.2f * e; unsafeAtomicAdd(&wsum[d * 4 + 1], expf(e));
    e = as.z + ad.z; e = e > 0.f ? e : 0.2f * e; unsafeAtomicAdd(&wsum[d * 4 + 2], expf(e));
    e = as.w + ad.w; e = e > 0.f ? e : 0.2f * e; unsafeAtomicAdd(&wsum[d * 4 + 3], expf(e));
}

// K6: seed accumulators with self-loop contributions; compute dinv  (wave per node)
__global__ __launch_bounds__(256) void k_init2(
    const float* __restrict__ hfeat, const float* __restrict__ gfeat,
    const float* __restrict__ a_src, const float* __restrict__ a_dst,
    const float* __restrict__ wsum, const float* __restrict__ deg,
    float* __restrict__ dinv, float* __restrict__ gat, float* __restrict__ gcn, int n)
{
    const int wave = threadIdx.x >> 6;
    const int lane = threadIdx.x & 63;
    const int node = blockIdx.x * 4 + wave;
    if (node >= n) return;
    float dv = rsqrtf(deg[node]);
    if (lane == 0) dinv[node] = dv;
    float selfnorm = dv * dv;
    int h0 = lane >> 5, h1 = h0 + 2;
    float e0 = a_src[node * 4 + h0] + a_dst[node * 4 + h0]; e0 = e0 > 0.f ? e0 : 0.2f * e0;
    float e1 = a_src[node * 4 + h1] + a_dst[node * 4 + h1]; e1 = e1 > 0.f ? e1 : 0.2f * e1;
    float al0 = expf(e0) / wsum[node * 4 + h0];
    float al1 = expf(e1) / wsum[node * 4 + h1];
    size_t base = (size_t)node * 128;
    gat[base + lane]      = al0 * hfeat[base + lane];
    gat[base + lane + 64] = al1 * hfeat[base + lane + 64];
    gcn[base + lane]      = selfnorm * gfeat[base + lane];
    gcn[base + lane + 64] = selfnorm * gfeat[base + lane + 64];
}

// K7: main edge aggregation (wave per edge; lane l owns channels l and l+64)
__global__ __launch_bounds__(256) void k_agg(
    const int* __restrict__ src, const int* __restrict__ dst,
    const float* __restrict__ hfeat, const float* __restrict__ gfeat,
    const float* __restrict__ a_src, const float* __restrict__ a_dst,
    const float* __restrict__ wsum, const float* __restrict__ dinv,
    float* __restrict__ gat, float* __restrict__ gcn, int E)
{
    const int e = blockIdx.x * 4 + (threadIdx.x >> 6);
    if (e >= E) return;
    const int lane = threadIdx.x & 63;
    const int s = src[e], d = dst[e];
    const int h0 = lane >> 5, h1 = h0 + 2;
    float e0 = a_src[s * 4 + h0] + a_dst[d * 4 + h0]; e0 = e0 > 0.f ? e0 : 0.2f * e0;
    float e1 = a_src[s * 4 + h1] + a_dst[d * 4 + h1]; e1 = e1 > 0.f ? e1 : 0.2f * e1;
    const float al0 = expf(e0) / wsum[d * 4 + h0];
    const float al1 = expf(e1) / wsum[d * 4 + h1];
    const float nm = dinv[s] * dinv[d];
    const size_t sb = (size_t)s * 128, db = (size_t)d * 128;
    unsafeAtomicAdd(&gat[db + lane],      al0 * hfeat[sb + lane]);
    unsafeAtomicAdd(&gat[db + lane + 64], al1 * hfeat[sb + lane + 64]);
    unsafeAtomicAdd(&gcn[db + lane],      nm * gfeat[sb + lane]);
    unsafeAtomicAdd(&gcn[db + lane + 64], nm * gfeat[sb + lane + 64]);
}

// K8: gate softmax + fuse + residual + LayerNorm  (wave per node)
__global__ __launch_bounds__(256) void k_final(
    const float* __restrict__ gat, const float* __restrict__ gcn,
    const float* __restrict__ x, const float* __restrict__ gat_bias,
    const float* __restrict__ gcn_bias, const float* __restrict__ gate_W,
    const float* __restrict__ gate_b, const float* __restrict__ gamma,
    const float* __restrict__ beta, float* __restrict__ out, int n)
{
    const int wave = threadIdx.x >> 6;
    const int lane = threadIdx.x & 63;
    const int node = blockIdx.x * 4 + wave;
    if (node >= n) return;
    const int c0 = lane, c1 = lane + 64;
    const size_t base = (size_t)node * 128;
    float ga0 = gat[base + c0] + gat_bias[c0];
    float ga1 = gat[base + c1] + gat_bias[c1];
    float gc0 = gcn[base + c0] + gcn_bias[c0];
    float gc1 = gcn[base + c1] + gcn_bias[c1];
    float z0 = ga0 * gate_W[c0 * 2]     + ga1 * gate_W[c1 * 2]
             + gc0 * gate_W[(128 + c0) * 2]     + gc1 * gate_W[(128 + c1) * 2];
    float z1 = ga0 * gate_W[c0 * 2 + 1] + ga1 * gate_W[c1 * 2 + 1]
             + gc0 * gate_W[(128 + c0) * 2 + 1] + gc1 * gate_W[(128 + c1) * 2 + 1];
    #pragma unroll
    for (int off = 32; off >= 1; off >>= 1) {
        z0 += __shfl_xor(z0, off);
        z1 += __shfl_xor(z1, off);
    }
    z0 += gate_b[0]; z1 += gate_b[1];
    float m = fmaxf(z0, z1);
    float ez0 = expf(z0 - m), ez1 = expf(z1 - m);
    float inv = 1.f / (ez0 + ez1);
    float g0 = ez0 * inv, g1 = ez1 * inv;

    float y0 = g0 * ga0 + g1 * gc0 + x[base + c0];
    float y1 = g0 * ga1 + g1 * gc1 + x[base + c1];

    float sum = y0 + y1;
    #pragma unroll
    for (int off = 32; off >= 1; off >>= 1) sum += __shfl_xor(sum, off);
    float mu = sum * (1.f / 128.f);
    float d0 = y0 - mu, d1 = y1 - mu;
    float sq = d0 * d0 + d1 * d1;
    #pragma unroll
    for (int off = 32; off >= 1; off >>= 1) sq += __shfl_xor(sq, off);
    float r = rsqrtf(sq * (1.f / 128.f) + 1e-5f);
    out[base + c0] = d0 * r * gamma[c0] + beta[c0];
    out[base + c1] = d1 * r * gamma[c1] + beta[c1];
}

extern "C" void kernel_launch(void* const* d_in, const int* in_sizes, int n_in,
                              void* d_out, int out_size, void* d_ws, size_t ws_size,
                              hipStream_t stream)
{
    const float* x        = (const float*)d_in[0];
    const float* gat_W    = (const float*)d_in[1];
    const float* att_src  = (const float*)d_in[2];
    const float* att_dst  = (const float*)d_in[3];
    const float* gat_bias = (const float*)d_in[4];
    const float* gcn_W    = (const float*)d_in[5];
    const float* gcn_bias = (const float*)d_in[6];
    const float* gate_W   = (const float*)d_in[7];
    const float* gate_b   = (const float*)d_in[8];
    const float* ln_gamma = (const float*)d_in[9];
    const float* ln_beta  = (const float*)d_in[10];
    const int*   edge     = (const int*)d_in[11];

    const int n = in_sizes[0] / 128;
    const int E = in_sizes[11] / 2;
    const int* src = edge;
    const int* dst = edge + E;

    float* ws = (float*)d_ws;
    float* hfeat = ws;  ws += (size_t)n * 128;
    float* gfeat = ws;  ws += (size_t)n * 128;
    float* gat   = ws;  ws += (size_t)n * 128;
    float* gcn   = ws;  ws += (size_t)n * 128;
    float* a_src = ws;  ws += (size_t)n * 4;
    float* a_dst = ws;  ws += (size_t)n * 4;
    float* wsum  = ws;  ws += (size_t)n * 4;
    float* deg   = ws;  ws += (size_t)n;
    float* dinv  = ws;  ws += (size_t)n;

    const int nb4 = (n + 3) / 4;
    k_gemm<<<(n + 31) / 32, 256, 0, stream>>>(x, gat_W, gcn_W, hfeat, gfeat, n);
    k_att<<<nb4, 256, 0, stream>>>(hfeat, att_src, att_dst, a_src, a_dst, n);
    k_nodeinit<<<(n + 255) / 256, 256, 0, stream>>>(a_src, a_dst, deg, wsum, n);
    k_deg<<<(E + 255) / 256, 256, 0, stream>>>(dst, deg, E);
    k_wsum<<<(E + 255) / 256, 256, 0, stream>>>(src, dst, a_src, a_dst, wsum, E);
    k_init2<<<nb4, 256, 0, stream>>>(hfeat, gfeat, a_src, a_dst, wsum, deg, dinv, gat, gcn, n);
    k_agg<<<(E + 3) / 4, 256, 0, stream>>>(src, dst, hfeat, gfeat, a_src, a_dst, wsum, dinv, gat, gcn, E);
    k_final<<<nb4, 256, 0, stream>>>(gat, gcn, x, gat_bias, gcn_bias, gate_W, gate_b,
                                     ln_gamma, ln_beta, (float*)d_out, n);
}

// Round 2
// 412.138 us; speedup vs baseline: 2.6040x; 2.6040x over previous
//
#include <hip/hip_runtime.h>
#include <math.h>

// ---------------------------------------------------------------------------
// Fused GAT(4 heads, 32 ch) + GCN + gated fusion + residual + LayerNorm
// N=50000, D=128, E=800000 (+N self-loops folded analytically).
// Round 2: atomic scatter -> CSR build + per-node register gather, with the
// gate/residual/LN epilogue fused into the gather kernel.
// ---------------------------------------------------------------------------

// K1: fused GEMM  h = x @ gat_W (128x128), g = x @ gcn_W (128x128)
__global__ __launch_bounds__(256) void k_gemm(
    const float* __restrict__ x, const float* __restrict__ Wg,
    const float* __restrict__ Wc, float* __restrict__ hfeat,
    float* __restrict__ gfeat, int n)
{
    __shared__ float xs[32][128];
    const int row0 = blockIdx.x * 32;
    const int t = threadIdx.x;

    #pragma unroll
    for (int i = 0; i < 16; ++i) {
        int idx = t + i * 256;
        int r = idx >> 7, c = idx & 127;
        int gr = row0 + r;
        xs[r][c] = (gr < n) ? x[(size_t)gr * 128 + c] : 0.f;
    }
    __syncthreads();

    float acc[32];
    #pragma unroll
    for (int r = 0; r < 32; ++r) acc[r] = 0.f;

    const float* Wp = (t < 128) ? (Wg + t) : (Wc + (t - 128));
    for (int k0 = 0; k0 < 128; k0 += 4) {
        float w0 = Wp[(k0 + 0) * 128];
        float w1 = Wp[(k0 + 1) * 128];
        float w2 = Wp[(k0 + 2) * 128];
        float w3 = Wp[(k0 + 3) * 128];
        #pragma unroll
        for (int r = 0; r < 32; ++r) {
            const float4 xv = *reinterpret_cast<const float4*>(&xs[r][k0]);
            acc[r] = fmaf(xv.x, w0, fmaf(xv.y, w1, fmaf(xv.z, w2, fmaf(xv.w, w3, acc[r]))));
        }
    }

    float* outp = (t < 128) ? (hfeat + t) : (gfeat + (t - 128));
    #pragma unroll
    for (int r = 0; r < 32; ++r) {
        int gr = row0 + r;
        if (gr < n) outp[(size_t)gr * 128] = acc[r];
    }
}

// K2: per-node attention logits a_src[n,4], a_dst[n,4]  (wave per node)
__global__ __launch_bounds__(256) void k_att(
    const float* __restrict__ hfeat, const float* __restrict__ att_src,
    const float* __restrict__ att_dst, float* __restrict__ a_src,
    float* __restrict__ a_dst, int n)
{
    const int wave = threadIdx.x >> 6;
    const int lane = threadIdx.x & 63;
    const int node = blockIdx.x * 4 + wave;
    if (node >= n) return;
    float h0 = hfeat[(size_t)node * 128 + lane];
    float h1 = hfeat[(size_t)node * 128 + lane + 64];
    float s0 = h0 * att_src[lane], s1 = h1 * att_src[lane + 64];
    float d0 = h0 * att_dst[lane], d1 = h1 * att_dst[lane + 64];
    #pragma unroll
    for (int off = 16; off >= 1; off >>= 1) {
        s0 += __shfl_xor(s0, off);
        s1 += __shfl_xor(s1, off);
        d0 += __shfl_xor(d0, off);
        d1 += __shfl_xor(d1, off);
    }
    if ((lane & 31) == 0) {
        int g = lane >> 5;
        a_src[node * 4 + g]     = s0;
        a_src[node * 4 + 2 + g] = s1;
        a_dst[node * 4 + g]     = d0;
        a_dst[node * 4 + 2 + g] = d1;
    }
}

// K3: histogram of incoming-edge counts (int atomics; counts pre-zeroed)
__global__ void k_hist(const int* __restrict__ dst, int* __restrict__ counts, int E)
{
    int i = blockIdx.x * blockDim.x + threadIdx.x;
    if (i < E) atomicAdd(&counts[dst[i]], 1);
}

// K4a: per-block (256-chunk) sums of counts
__global__ __launch_bounds__(256) void k_scan1(const int* __restrict__ counts,
                                               int* __restrict__ bsum, int n)
{
    __shared__ int sh[256];
    int t = threadIdx.x;
    int i = blockIdx.x * 256 + t;
    sh[t] = (i < n) ? counts[i] : 0;
    __syncthreads();
    #pragma unroll
    for (int off = 128; off >= 1; off >>= 1) {
        if (t < off) sh[t] += sh[t + off];
        __syncthreads();
    }
    if (t == 0) bsum[blockIdx.x] = sh[0];
}

// K4b: exclusive scan of block sums (nb <= 256), single block
__global__ __launch_bounds__(256) void k_scan2(int* __restrict__ bsum, int nb)
{
    __shared__ int sh[256];
    int t = threadIdx.x;
    int v = (t < nb) ? bsum[t] : 0;
    sh[t] = v;
    __syncthreads();
    #pragma unroll
    for (int off = 1; off < 256; off <<= 1) {
        int u = (t >= off) ? sh[t - off] : 0;
        __syncthreads();
        sh[t] += u;
        __syncthreads();
    }
    if (t < nb) bsum[t] = sh[t] - v;   // exclusive
}

// K4c: rowptr (exclusive scan) + cursor copy + dinv = rsqrt(1+count)
__global__ __launch_bounds__(256) void k_scan3(
    const int* __restrict__ counts, const int* __restrict__ bsum,
    int* __restrict__ rowptr, int* __restrict__ cursor,
    float* __restrict__ dinv, int n)
{
    __shared__ int sh[256];
    int t = threadIdx.x;
    int i = blockIdx.x * 256 + t;
    int v = (i < n) ? counts[i] : 0;
    sh[t] = v;
    __syncthreads();
    #pragma unroll
    for (int off = 1; off < 256; off <<= 1) {
        int u = (t >= off) ? sh[t - off] : 0;
        __syncthreads();
        sh[t] += u;
        __syncthreads();
    }
    if (i < n) {
        int excl = bsum[blockIdx.x] + sh[t] - v;
        rowptr[i] = excl;
        cursor[i] = excl;
        dinv[i] = rsqrtf((float)(1 + v));   // self-loop included in degree
        if (i == n - 1) rowptr[n] = excl + v;
    }
}

// K5: scatter src indices into CSR order (cursor = rowptr copy)
__global__ void k_scatter(const int* __restrict__ src, const int* __restrict__ dst,
                          int* __restrict__ cursor, int* __restrict__ esorted, int E)
{
    int i = blockIdx.x * blockDim.x + threadIdx.x;
    if (i < E) {
        int p = atomicAdd(&cursor[dst[i]], 1);
        esorted[p] = src[i];
    }
}

// K6: fused per-node aggregation + gate + residual + LayerNorm (wave per node)
// lane owns channels {lane, lane+64}; heads: h(c)=c>>5 -> h0=lane>>5, h1=h0+2
__global__ __launch_bounds__(256) void k_fused(
    const int* __restrict__ esorted, const int* __restrict__ rowptr,
    const float* __restrict__ hfeat, const float* __restrict__ gfeat,
    const float* __restrict__ a_src, const float* __restrict__ a_dst,
    const float* __restrict__ dinv, const float* __restrict__ x,
    const float* __restrict__ gat_bias, const float* __restrict__ gcn_bias,
    const float* __restrict__ gate_W, const float* __restrict__ gate_b,
    const float* __restrict__ gamma, const float* __restrict__ beta,
    float* __restrict__ out, int n)
{
    const int lane = threadIdx.x & 63;
    const int node = blockIdx.x * 4 + (threadIdx.x >> 6);
    if (node >= n) return;

    const int beg = rowptr[node], end = rowptr[node + 1];
    const float ad0 = a_dst[node * 4 + 0], ad1 = a_dst[node * 4 + 1];
    const float ad2 = a_dst[node * 4 + 2], ad3 = a_dst[node * 4 + 3];

    // ---- pass 1: softmax denominators for all 4 heads (lane-parallel) ----
    float ws0 = 0.f, ws1 = 0.f, ws2 = 0.f, ws3 = 0.f;
    for (int j = beg + lane; j < end; j += 64) {
        int s = esorted[j];
        const float4 as = *reinterpret_cast<const float4*>(a_src + (size_t)s * 4);
        float e;
        e = as.x + ad0; e = e > 0.f ? e : 0.2f * e; ws0 += __expf(e);
        e = as.y + ad1; e = e > 0.f ? e : 0.2f * e; ws1 += __expf(e);
        e = as.z + ad2; e = e > 0.f ? e : 0.2f * e; ws2 += __expf(e);
        e = as.w + ad3; e = e > 0.f ? e : 0.2f * e; ws3 += __expf(e);
    }
    #pragma unroll
    for (int off = 32; off >= 1; off >>= 1) {
        ws0 += __shfl_xor(ws0, off); ws1 += __shfl_xor(ws1, off);
        ws2 += __shfl_xor(ws2, off); ws3 += __shfl_xor(ws3, off);
    }
    // self-loop terms
    const float s0v = a_src[node * 4 + 0], s1v = a_src[node * 4 + 1];
    const float s2v = a_src[node * 4 + 2], s3v = a_src[node * 4 + 3];
    float e0s = s0v + ad0; e0s = e0s > 0.f ? e0s : 0.2f * e0s; float ex0 = __expf(e0s);
    float e1s = s1v + ad1; e1s = e1s > 0.f ? e1s : 0.2f * e1s; float ex1 = __expf(e1s);
    float e2s = s2v + ad2; e2s = e2s > 0.f ? e2s : 0.2f * e2s; float ex2 = __expf(e2s);
    float e3s = s3v + ad3; e3s = e3s > 0.f ? e3s : 0.2f * e3s; float ex3 = __expf(e3s);
    ws0 += ex0; ws1 += ex1; ws2 += ex2; ws3 += ex3;

    // per-lane head selection (named scalars only -> no scratch)
    const bool hi = (lane >= 32);
    const float invw0 = 1.f / (hi ? ws1 : ws0);
    const float invw1 = 1.f / (hi ? ws3 : ws2);
    const float adh0  = hi ? ad1 : ad0;
    const float adh1  = hi ? ad3 : ad2;
    const float exs0  = hi ? ex1 : ex0;
    const float exs1  = hi ? ex3 : ex2;

    const float dvd = dinv[node];
    const size_t nbase = (size_t)node * 128;

    // ---- self-loop contributions ----
    float acc0  = exs0 * invw0 * hfeat[nbase + lane];
    float acc1  = exs1 * invw1 * hfeat[nbase + lane + 64];
    float accg0 = dvd * dvd * gfeat[nbase + lane];
    float accg1 = dvd * dvd * gfeat[nbase + lane + 64];

    // ---- pass 2: gather over incoming edges ----
    const int off_a0 = hi ? 1 : 0;
    const int off_a1 = hi ? 3 : 2;
    for (int j = beg; j < end; ++j) {
        int s = esorted[j];                        // uniform across wave
        float a0 = a_src[(size_t)s * 4 + off_a0];
        float a1 = a_src[(size_t)s * 4 + off_a1];
        float e0 = a0 + adh0; e0 = e0 > 0.f ? e0 : 0.2f * e0;
        float e1 = a1 + adh1; e1 = e1 > 0.f ? e1 : 0.2f * e1;
        float al0 = __expf(e0) * invw0;
        float al1 = __expf(e1) * invw1;
        float nm = dinv[s] * dvd;
        size_t sb = (size_t)s * 128;
        acc0  += al0 * hfeat[sb + lane];
        acc1  += al1 * hfeat[sb + lane + 64];
        accg0 += nm * gfeat[sb + lane];
        accg1 += nm * gfeat[sb + lane + 64];
    }

    // ---- epilogue: gate softmax + fuse + residual + LayerNorm ----
    const int c0 = lane, c1 = lane + 64;
    float ga0 = acc0 + gat_bias[c0];
    float ga1 = acc1 + gat_bias[c1];
    float gc0 = accg0 + gcn_bias[c0];
    float gc1 = accg1 + gcn_bias[c1];
    float z0 = ga0 * gate_W[c0 * 2]     + ga1 * gate_W[c1 * 2]
             + gc0 * gate_W[(128 + c0) * 2]     + gc1 * gate_W[(192 + lane) * 2];
    float z1 = ga0 * gate_W[c0 * 2 + 1] + ga1 * gate_W[c1 * 2 + 1]
             + gc0 * gate_W[(128 + c0) * 2 + 1] + gc1 * gate_W[(192 + lane) * 2 + 1];
    #pragma unroll
    for (int off = 32; off >= 1; off >>= 1) {
        z0 += __shfl_xor(z0, off);
        z1 += __shfl_xor(z1, off);
    }
    z0 += gate_b[0]; z1 += gate_b[1];
    float m = fmaxf(z0, z1);
    float ez0 = __expf(z0 - m), ez1 = __expf(z1 - m);
    float inv = 1.f / (ez0 + ez1);
    float g0 = ez0 * inv, g1 = ez1 * inv;

    float y0 = g0 * ga0 + g1 * gc0 + x[nbase + c0];
    float y1 = g0 * ga1 + g1 * gc1 + x[nbase + c1];

    float sum = y0 + y1;
    #pragma unroll
    for (int off = 32; off >= 1; off >>= 1) sum += __shfl_xor(sum, off);
    float mu = sum * (1.f / 128.f);
    float d0 = y0 - mu, d1 = y1 - mu;
    float sq = d0 * d0 + d1 * d1;
    #pragma unroll
    for (int off = 32; off >= 1; off >>= 1) sq += __shfl_xor(sq, off);
    float r = rsqrtf(sq * (1.f / 128.f) + 1e-5f);
    out[nbase + c0] = d0 * r * gamma[c0] + beta[c0];
    out[nbase + c1] = d1 * r * gamma[c1] + beta[c1];
}

extern "C" void kernel_launch(void* const* d_in, const int* in_sizes, int n_in,
                              void* d_out, int out_size, void* d_ws, size_t ws_size,
                              hipStream_t stream)
{
    const float* x        = (const float*)d_in[0];
    const float* gat_W    = (const float*)d_in[1];
    const float* att_src  = (const float*)d_in[2];
    const float* att_dst  = (const float*)d_in[3];
    const float* gat_bias = (const float*)d_in[4];
    const float* gcn_W    = (const float*)d_in[5];
    const float* gcn_bias = (const float*)d_in[6];
    const float* gate_W   = (const float*)d_in[7];
    const float* gate_b   = (const float*)d_in[8];
    const float* ln_gamma = (const float*)d_in[9];
    const float* ln_beta  = (const float*)d_in[10];
    const int*   edge     = (const int*)d_in[11];

    const int n = in_sizes[0] / 128;
    const int E = in_sizes[11] / 2;
    const int* src = edge;
    const int* dst = edge + E;
    const int nb_chunks = (n + 255) / 256;   // 196 for n=50000 (<=256 required)

    char* w = (char*)d_ws;
    float* hfeat   = (float*)w;  w += (size_t)n * 128 * 4;
    float* gfeat   = (float*)w;  w += (size_t)n * 128 * 4;
    float* a_src   = (float*)w;  w += (size_t)n * 4 * 4;
    float* a_dst   = (float*)w;  w += (size_t)n * 4 * 4;
    float* dinv    = (float*)w;  w += (size_t)n * 4;
    int*   counts  = (int*)w;    w += (size_t)n * 4;
    int*   bsum    = (int*)w;    w += (size_t)256 * 4;
    int*   rowptr  = (int*)w;    w += (size_t)(n + 1) * 4;
    int*   cursor  = (int*)w;    w += (size_t)n * 4;
    int*   esorted = (int*)w;    w += (size_t)E * 4;

    hipMemsetAsync(counts, 0, (size_t)n * 4, stream);

    const int nb4 = (n + 3) / 4;
    k_gemm<<<(n + 31) / 32, 256, 0, stream>>>(x, gat_W, gcn_W, hfeat, gfeat, n);
    k_att<<<nb4, 256, 0, stream>>>(hfeat, att_src, att_dst, a_src, a_dst, n);
    k_hist<<<(E + 255) / 256, 256, 0, stream>>>(dst, counts, E);
    k_scan1<<<nb_chunks, 256, 0, stream>>>(counts, bsum, n);
    k_scan2<<<1, 256, 0, stream>>>(bsum, nb_chunks);
    k_scan3<<<nb_chunks, 256, 0, stream>>>(counts, bsum, rowptr, cursor, dinv, n);
    k_scatter<<<(E + 255) / 256, 256, 0, stream>>>(src, dst, cursor, esorted, E);
    k_fused<<<nb4, 256, 0, stream>>>(esorted, rowptr, hfeat, gfeat, a_src, a_dst,
                                     dinv, x, gat_bias, gcn_bias, gate_W, gate_b,
                                     ln_gamma, ln_beta, (float*)d_out, n);
}

// Round 3
// 310.643 us; speedup vs baseline: 3.4548x; 1.3267x over previous
//
#include <hip/hip_runtime.h>
#include <math.h>

// ---------------------------------------------------------------------------
// Fused GAT(4 heads, 32 ch) + GCN + gated fusion + residual + LayerNorm
// N=50000, D=128, E=800000 (+N self-loops folded analytically).
// Round 3: bf16-packed features, single-pass deferred-normalization gather
// with 4x unroll (MLP), GEMM+att+hist fused into one launch.
// ---------------------------------------------------------------------------

__device__ __forceinline__ unsigned short f2bf(float f) {
    unsigned int u = __float_as_uint(f);
    u += 0x7fffu + ((u >> 16) & 1u);          // round-to-nearest-even
    return (unsigned short)(u >> 16);
}
__device__ __forceinline__ float bf2f(unsigned short v) {
    return __uint_as_float(((unsigned int)v) << 16);
}

// K1: fused  [hist blocks] + [GEMM h|g -> packed bf16 + attention logits]
// GEMM tile: 32 rows x 256 cols per block (cols 0-127 h, 128-255 g).
// Thread t: rows 8*(t>>6)..+7, cols 4*(t&63)..+3.  acc[8] = float4 (4 cols).
// Packed layout pk[node][256]: [0:64)=h[0:64), [64:128)=h[64:128),
//                              [128:192)=g[0:64), [192:256)=g[64:128).
__global__ __launch_bounds__(256) void k_combo(
    const float* __restrict__ x, const float* __restrict__ Wg,
    const float* __restrict__ Wc, const float* __restrict__ att_src,
    const float* __restrict__ att_dst, const int* __restrict__ dst,
    int* __restrict__ counts, unsigned short* __restrict__ pk,
    float* __restrict__ a_src, float* __restrict__ a_dst,
    int n, int E, int histBlocks)
{
    const int t = threadIdx.x;
    if (blockIdx.x < histBlocks) {
        int i = blockIdx.x * 256 + t;
        const int stride = histBlocks * 256;
        for (; i < E; i += stride) atomicAdd(&counts[dst[i]], 1);
        return;
    }
    const int gb = blockIdx.x - histBlocks;
    const int row0 = gb * 32;

    __shared__ float xs[32][128];
    {
        const float4* xv = reinterpret_cast<const float4*>(x);
        #pragma unroll
        for (int i = 0; i < 4; ++i) {
            int q = t + i * 256;           // 0..1023
            int r = q >> 5;                // 0..31
            int c4 = q & 31;               // float4 column
            float4 v = (row0 + r < n) ? xv[(size_t)(row0 + r) * 32 + c4]
                                      : make_float4(0.f, 0.f, 0.f, 0.f);
            *reinterpret_cast<float4*>(&xs[r][c4 * 4]) = v;
        }
    }
    __syncthreads();

    const int cl = t & 63;
    const int rg = t >> 6;
    const float* Wbase = (cl < 32) ? (Wg + 4 * cl) : (Wc + 4 * cl - 128);

    float4 acc[8];
    #pragma unroll
    for (int r = 0; r < 8; ++r) acc[r] = make_float4(0.f, 0.f, 0.f, 0.f);

    for (int k0 = 0; k0 < 128; k0 += 4) {
        const float4 w0 = *reinterpret_cast<const float4*>(Wbase + (k0 + 0) * 128);
        const float4 w1 = *reinterpret_cast<const float4*>(Wbase + (k0 + 1) * 128);
        const float4 w2 = *reinterpret_cast<const float4*>(Wbase + (k0 + 2) * 128);
        const float4 w3 = *reinterpret_cast<const float4*>(Wbase + (k0 + 3) * 128);
        #pragma unroll
        for (int r = 0; r < 8; ++r) {
            const float4 xv4 = *reinterpret_cast<const float4*>(&xs[rg * 8 + r][k0]);
            acc[r].x += xv4.x * w0.x + xv4.y * w1.x + xv4.z * w2.x + xv4.w * w3.x;
            acc[r].y += xv4.x * w0.y + xv4.y * w1.y + xv4.z * w2.y + xv4.w * w3.y;
            acc[r].z += xv4.x * w0.z + xv4.y * w1.z + xv4.z * w2.z + xv4.w * w3.z;
            acc[r].w += xv4.x * w0.w + xv4.y * w1.w + xv4.z * w2.w + xv4.w * w3.w;
        }
    }

    // attention logits: cols 4cl..4cl+3 are h-columns iff cl<32; head = cl>>3
    if (cl < 32) {
        const int head = cl >> 3;
        const float4 as4 = *reinterpret_cast<const float4*>(att_src + 4 * cl);
        const float4 ad4 = *reinterpret_cast<const float4*>(att_dst + 4 * cl);
        #pragma unroll
        for (int r = 0; r < 8; ++r) {
            float vs = acc[r].x * as4.x + acc[r].y * as4.y + acc[r].z * as4.z + acc[r].w * as4.w;
            float vd = acc[r].x * ad4.x + acc[r].y * ad4.y + acc[r].z * ad4.z + acc[r].w * ad4.w;
            vs += __shfl_xor(vs, 1); vs += __shfl_xor(vs, 2); vs += __shfl_xor(vs, 4);
            vd += __shfl_xor(vd, 1); vd += __shfl_xor(vd, 2); vd += __shfl_xor(vd, 4);
            const int row = row0 + rg * 8 + r;
            if ((cl & 7) == 0 && row < n) {
                a_src[row * 4 + head] = vs;
                a_dst[row * 4 + head] = vd;
            }
        }
    }

    // pack to bf16: global col c = 4cl+j -> slot = cl>>4, pos = (4cl)&63 (+j)
    const int slot = cl >> 4;
    const int lpos = (4 * cl) & 63;
    #pragma unroll
    for (int r = 0; r < 8; ++r) {
        const int row = row0 + rg * 8 + r;
        if (row < n) {
            ushort4 u;
            u.x = f2bf(acc[r].x); u.y = f2bf(acc[r].y);
            u.z = f2bf(acc[r].z); u.w = f2bf(acc[r].w);
            *reinterpret_cast<ushort4*>(pk + (size_t)row * 256 + slot * 64 + lpos) = u;
        }
    }
}

// K2a: per-256-chunk sums of counts
__global__ __launch_bounds__(256) void k_scan1(const int* __restrict__ counts,
                                               int* __restrict__ bsum, int n)
{
    __shared__ int sh[256];
    int t = threadIdx.x;
    int i = blockIdx.x * 256 + t;
    sh[t] = (i < n) ? counts[i] : 0;
    __syncthreads();
    #pragma unroll
    for (int off = 128; off >= 1; off >>= 1) {
        if (t < off) sh[t] += sh[t + off];
        __syncthreads();
    }
    if (t == 0) bsum[blockIdx.x] = sh[0];
}

// K2b: exclusive scan of block sums (nb <= 256), single block
__global__ __launch_bounds__(256) void k_scan2(int* __restrict__ bsum, int nb)
{
    __shared__ int sh[256];
    int t = threadIdx.x;
    int v = (t < nb) ? bsum[t] : 0;
    sh[t] = v;
    __syncthreads();
    #pragma unroll
    for (int off = 1; off < 256; off <<= 1) {
        int u = (t >= off) ? sh[t - off] : 0;
        __syncthreads();
        sh[t] += u;
        __syncthreads();
    }
    if (t < nb) bsum[t] = sh[t] - v;   // exclusive
}

// K2c: rowptr + cursor + dinv = rsqrt(1+deg)
__global__ __launch_bounds__(256) void k_scan3(
    const int* __restrict__ counts, const int* __restrict__ bsum,
    int* __restrict__ rowptr, int* __restrict__ cursor,
    float* __restrict__ dinv, int n)
{
    __shared__ int sh[256];
    int t = threadIdx.x;
    int i = blockIdx.x * 256 + t;
    int v = (i < n) ? counts[i] : 0;
    sh[t] = v;
    __syncthreads();
    #pragma unroll
    for (int off = 1; off < 256; off <<= 1) {
        int u = (t >= off) ? sh[t - off] : 0;
        __syncthreads();
        sh[t] += u;
        __syncthreads();
    }
    if (i < n) {
        int excl = bsum[blockIdx.x] + sh[t] - v;
        rowptr[i] = excl;
        cursor[i] = excl;
        dinv[i] = rsqrtf((float)(1 + v));
        if (i == n - 1) rowptr[n] = excl + v;
    }
}

// K3: scatter src indices into CSR order
__global__ void k_scatter(const int* __restrict__ src, const int* __restrict__ dst,
                          int* __restrict__ cursor, int* __restrict__ esorted, int E)
{
    int i = blockIdx.x * blockDim.x + threadIdx.x;
    if (i < E) {
        int p = atomicAdd(&cursor[dst[i]], 1);
        esorted[p] = src[i];
    }
}

// K4: single-pass gather (deferred softmax norm) + gate + residual + LN
// wave per node; lane owns channels {lane, lane+64}; head sel = lane>>5
__global__ __launch_bounds__(256) void k_fused(
    const int* __restrict__ esorted, const int* __restrict__ rowptr,
    const unsigned short* __restrict__ pk,
    const float* __restrict__ a_src, const float* __restrict__ a_dst,
    const float* __restrict__ dinv, const float* __restrict__ x,
    const float* __restrict__ gat_bias, const float* __restrict__ gcn_bias,
    const float* __restrict__ gate_W, const float* __restrict__ gate_b,
    const float* __restrict__ gamma, const float* __restrict__ beta,
    float* __restrict__ out, int n)
{
    const int lane = threadIdx.x & 63;
    const int node = blockIdx.x * 4 + (threadIdx.x >> 6);
    if (node >= n) return;

    const int sel = lane >> 5;                  // head = sel (lo) / sel+2 (hi)
    const float adh0 = a_dst[node * 4 + sel];
    const float adh1 = a_dst[node * 4 + sel + 2];

    const int beg = rowptr[node], end = rowptr[node + 1];

    float acc0 = 0.f, acc1 = 0.f, accg0 = 0.f, accg1 = 0.f, ws0 = 0.f, ws1 = 0.f;

#define EDGE_BODY(H0, H1, G0, G1, A0, A1, DI)                           \
    {                                                                   \
        float e0 = (A0) + adh0; e0 = e0 > 0.f ? e0 : 0.2f * e0;         \
        float e1 = (A1) + adh1; e1 = e1 > 0.f ? e1 : 0.2f * e1;         \
        float w0 = __expf(e0), w1 = __expf(e1);                         \
        ws0 += w0; ws1 += w1;                                           \
        acc0 = fmaf(w0, (H0), acc0);  acc1 = fmaf(w1, (H1), acc1);      \
        accg0 = fmaf((DI), (G0), accg0); accg1 = fmaf((DI), (G1), accg1);\
    }

    int j = beg;
    for (; j + 4 <= end; j += 4) {
        const int s0 = esorted[j], s1 = esorted[j + 1], s2 = esorted[j + 2], s3 = esorted[j + 3];
        const unsigned short* p0 = pk + (size_t)s0 * 256;
        const unsigned short* p1 = pk + (size_t)s1 * 256;
        const unsigned short* p2 = pk + (size_t)s2 * 256;
        const unsigned short* p3 = pk + (size_t)s3 * 256;
        float h00 = bf2f(p0[lane]), h01 = bf2f(p0[64 + lane]), g00 = bf2f(p0[128 + lane]), g01 = bf2f(p0[192 + lane]);
        float h10 = bf2f(p1[lane]), h11 = bf2f(p1[64 + lane]), g10 = bf2f(p1[128 + lane]), g11 = bf2f(p1[192 + lane]);
        float h20 = bf2f(p2[lane]), h21 = bf2f(p2[64 + lane]), g20 = bf2f(p2[128 + lane]), g21 = bf2f(p2[192 + lane]);
        float h30 = bf2f(p3[lane]), h31 = bf2f(p3[64 + lane]), g30 = bf2f(p3[128 + lane]), g31 = bf2f(p3[192 + lane]);
        float a00 = a_src[s0 * 4 + sel], a01 = a_src[s0 * 4 + sel + 2];
        float a10 = a_src[s1 * 4 + sel], a11 = a_src[s1 * 4 + sel + 2];
        float a20 = a_src[s2 * 4 + sel], a21 = a_src[s2 * 4 + sel + 2];
        float a30 = a_src[s3 * 4 + sel], a31 = a_src[s3 * 4 + sel + 2];
        float d0 = dinv[s0], d1 = dinv[s1], d2 = dinv[s2], d3 = dinv[s3];
        EDGE_BODY(h00, h01, g00, g01, a00, a01, d0);
        EDGE_BODY(h10, h11, g10, g11, a10, a11, d1);
        EDGE_BODY(h20, h21, g20, g21, a20, a21, d2);
        EDGE_BODY(h30, h31, g30, g31, a30, a31, d3);
    }
    for (; j < end; ++j) {
        const int s = esorted[j];
        const unsigned short* p = pk + (size_t)s * 256;
        float h0 = bf2f(p[lane]), h1 = bf2f(p[64 + lane]);
        float g0 = bf2f(p[128 + lane]), g1 = bf2f(p[192 + lane]);
        float a0 = a_src[s * 4 + sel], a1 = a_src[s * 4 + sel + 2];
        float di = dinv[s];
        EDGE_BODY(h0, h1, g0, g1, a0, a1, di);
    }

    // self loop
    const float dvd = dinv[node];
    {
        const unsigned short* p = pk + (size_t)node * 256;
        float h0 = bf2f(p[lane]), h1 = bf2f(p[64 + lane]);
        float g0 = bf2f(p[128 + lane]), g1 = bf2f(p[192 + lane]);
        float a0 = a_src[node * 4 + sel], a1 = a_src[node * 4 + sel + 2];
        EDGE_BODY(h0, h1, g0, g1, a0, a1, dvd);
    }
#undef EDGE_BODY

    // ---- epilogue: gate softmax + fuse + residual + LayerNorm ----
    const int c0 = lane, c1 = lane + 64;
    const size_t nbase = (size_t)node * 128;
    float ga0 = acc0 / ws0 + gat_bias[c0];
    float ga1 = acc1 / ws1 + gat_bias[c1];
    float gc0 = accg0 * dvd + gcn_bias[c0];
    float gc1 = accg1 * dvd + gcn_bias[c1];
    float z0 = ga0 * gate_W[c0 * 2]     + ga1 * gate_W[c1 * 2]
             + gc0 * gate_W[(128 + c0) * 2]     + gc1 * gate_W[(192 + lane) * 2];
    float z1 = ga0 * gate_W[c0 * 2 + 1] + ga1 * gate_W[c1 * 2 + 1]
             + gc0 * gate_W[(128 + c0) * 2 + 1] + gc1 * gate_W[(192 + lane) * 2 + 1];
    #pragma unroll
    for (int off = 32; off >= 1; off >>= 1) {
        z0 += __shfl_xor(z0, off);
        z1 += __shfl_xor(z1, off);
    }
    z0 += gate_b[0]; z1 += gate_b[1];
    float m = fmaxf(z0, z1);
    float ez0 = __expf(z0 - m), ez1 = __expf(z1 - m);
    float inv = 1.f / (ez0 + ez1);
    float g0 = ez0 * inv, g1 = ez1 * inv;

    float y0 = g0 * ga0 + g1 * gc0 + x[nbase + c0];
    float y1 = g0 * ga1 + g1 * gc1 + x[nbase + c1];

    float sum = y0 + y1;
    #pragma unroll
    for (int off = 32; off >= 1; off >>= 1) sum += __shfl_xor(sum, off);
    float mu = sum * (1.f / 128.f);
    float d0v = y0 - mu, d1v = y1 - mu;
    float sq = d0v * d0v + d1v * d1v;
    #pragma unroll
    for (int off = 32; off >= 1; off >>= 1) sq += __shfl_xor(sq, off);
    float r = rsqrtf(sq * (1.f / 128.f) + 1e-5f);
    out[nbase + c0] = d0v * r * gamma[c0] + beta[c0];
    out[nbase + c1] = d1v * r * gamma[c1] + beta[c1];
}

extern "C" void kernel_launch(void* const* d_in, const int* in_sizes, int n_in,
                              void* d_out, int out_size, void* d_ws, size_t ws_size,
                              hipStream_t stream)
{
    const float* x        = (const float*)d_in[0];
    const float* gat_W    = (const float*)d_in[1];
    const float* att_src  = (const float*)d_in[2];
    const float* att_dst  = (const float*)d_in[3];
    const float* gat_bias = (const float*)d_in[4];
    const float* gcn_W    = (const float*)d_in[5];
    const float* gcn_bias = (const float*)d_in[6];
    const float* gate_W   = (const float*)d_in[7];
    const float* gate_b   = (const float*)d_in[8];
    const float* ln_gamma = (const float*)d_in[9];
    const float* ln_beta  = (const float*)d_in[10];
    const int*   edge     = (const int*)d_in[11];

    const int n = in_sizes[0] / 128;
    const int E = in_sizes[11] / 2;
    const int* src = edge;
    const int* dst = edge + E;
    const int nb_chunks = (n + 255) / 256;   // 196 for n=50000 (<=256 required)

    char* w = (char*)d_ws;
    unsigned short* pk = (unsigned short*)w;  w += (size_t)n * 256 * 2;
    float* a_src   = (float*)w;  w += (size_t)n * 4 * 4;
    float* a_dst   = (float*)w;  w += (size_t)n * 4 * 4;
    float* dinv    = (float*)w;  w += (size_t)n * 4;
    int*   counts  = (int*)w;    w += (size_t)n * 4;
    int*   bsum    = (int*)w;    w += (size_t)256 * 4;
    int*   rowptr  = (int*)w;    w += (size_t)(n + 1) * 4;
    int*   cursor  = (int*)w;    w += (size_t)n * 4;
    int*   esorted = (int*)w;    w += (size_t)E * 4;

    hipMemsetAsync(counts, 0, (size_t)n * 4, stream);

    const int histBlocks = 512;
    const int gemmBlocks = (n + 31) / 32;
    k_combo<<<histBlocks + gemmBlocks, 256, 0, stream>>>(
        x, gat_W, gcn_W, att_src, att_dst, dst, counts, pk, a_src, a_dst, n, E, histBlocks);
    k_scan1<<<nb_chunks, 256, 0, stream>>>(counts, bsum, n);
    k_scan2<<<1, 256, 0, stream>>>(bsum, nb_chunks);
    k_scan3<<<nb_chunks, 256, 0, stream>>>(counts, bsum, rowptr, cursor, dinv, n);
    k_scatter<<<(E + 255) / 256, 256, 0, stream>>>(src, dst, cursor, esorted, E);
    k_fused<<<(n + 3) / 4, 256, 0, stream>>>(esorted, rowptr, pk, a_src, a_dst,
                                             dinv, x, gat_bias, gcn_bias, gate_W, gate_b,
                                             ln_gamma, ln_beta, (float*)d_out, n);
}

// Round 8
// 268.105 us; speedup vs baseline: 4.0029x; 1.1587x over previous
//
#include <hip/hip_runtime.h>
#include <math.h>

// ---------------------------------------------------------------------------
// Fused GAT(4 heads, 32 ch) + GCN + gated fusion + residual + LayerNorm
// N=50000, D=128, E=800000 (+N self-loops folded analytically).
// Round 4 kernel, fifth submission (four GPU acquisition timeouts): MFMA
// GEMM (bf16, 16x16x32) for the feature transform; k_fused re-laned so each
// lane owns channel pair {2l,2l+1} (one head) -> half the VMEM instructions
// in the gather loop.
// ---------------------------------------------------------------------------

typedef __attribute__((ext_vector_type(8))) short    bf16x8;
typedef __attribute__((ext_vector_type(4))) float    f32x4;
typedef __attribute__((ext_vector_type(8))) unsigned short u16x8;

__device__ __forceinline__ unsigned short f2bf(float f) {
    unsigned int u = __float_as_uint(f);
    u += 0x7fffu + ((u >> 16) & 1u);          // round-to-nearest-even
    return (unsigned short)(u >> 16);
}
__device__ __forceinline__ float bfhi(unsigned int u) {   // high ushort -> float
    return __uint_as_float(u & 0xffff0000u);
}
__device__ __forceinline__ float bflo(unsigned int u) {   // low ushort -> float
    return __uint_as_float(u << 16);
}

// K0: prep -- Wt[256][128] bf16 (Wt[n][k] = W[k][n]; n<128 -> gat_W, else gcn_W)
//            + zero the counts array (replaces hipMemset).
__global__ __launch_bounds__(256) void k_prep(
    const float* __restrict__ Wg, const float* __restrict__ Wc,
    unsigned short* __restrict__ wt, int* __restrict__ counts, int n)
{
    const int t = blockIdx.x * 256 + threadIdx.x;   // 16 blocks -> 0..4095
    const int nn = t >> 4;
    const int k0 = (t & 15) * 8;
    const float* Wsrc = (nn < 128) ? (Wg + nn) : (Wc + (nn - 128));
    u16x8 u;
    #pragma unroll
    for (int j = 0; j < 8; ++j) u[j] = f2bf(Wsrc[(size_t)(k0 + j) * 128]);
    *reinterpret_cast<u16x8*>(wt + (size_t)t * 8) = u;
    for (int i = t; i < n; i += 4096) counts[i] = 0;
}

// K1: [hist blocks] + [MFMA GEMM -> packed bf16 pk + attention logits]
// GEMM: 64 rows/block (4 waves x 16), 256 cols, K=128 (4 steps of 32).
// Wt staged in LDS with XOR swizzle byte ^= (n&7)<<4 (breaks 256B-stride
// bank conflicts on B-frag ds_read_b128).
__global__ __launch_bounds__(256) void k_combo(
    const float* __restrict__ x, const unsigned short* __restrict__ wt,
    const float* __restrict__ att_src, const float* __restrict__ att_dst,
    const int* __restrict__ dst, int* __restrict__ counts,
    unsigned short* __restrict__ pk, float* __restrict__ a_src,
    float* __restrict__ a_dst, int n, int E, int histBlocks)
{
    __shared__ unsigned short wlds[32768];          // 64 KB
    const int t = threadIdx.x;

    if (blockIdx.x < histBlocks) {
        int i = blockIdx.x * 256 + t;
        const int stride = histBlocks * 256;
        for (; i < E; i += stride) atomicAdd(&counts[dst[i]], 1);
        return;
    }

    // ---- stage Wt -> LDS (swizzled) ----
    char* lbase = (char*)wlds;
    #pragma unroll
    for (int i = 0; i < 16; ++i) {
        const int ch = i * 256 + t;                 // 16B chunk id, 0..4095
        const int nn = ch >> 4;                     // Wt row (output col)
        const int off = (ch & 15) * 16;             // byte offset within row
        const int byte = (nn * 256 + off) ^ ((nn & 7) << 4);
        *reinterpret_cast<u16x8*>(lbase + byte) =
            *reinterpret_cast<const u16x8*>(wt + (size_t)ch * 8);
    }
    __syncthreads();

    const int gb = blockIdx.x - histBlocks;
    const int l = t & 63;
    const int row0 = gb * 64 + (t >> 6) * 16;       // this wave's 16 rows
    const int arow = row0 + (l & 15);
    const bool av = arow < n;
    const float* xp = x + (size_t)arow * 128 + (l >> 4) * 8;

    // ---- A fragments straight from global (fp32 -> bf16 in-register) ----
    bf16x8 afr[4];
    #pragma unroll
    for (int ks = 0; ks < 4; ++ks) {
        float4 u0 = av ? *reinterpret_cast<const float4*>(xp + ks * 32)
                       : make_float4(0.f, 0.f, 0.f, 0.f);
        float4 u1 = av ? *reinterpret_cast<const float4*>(xp + ks * 32 + 4)
                       : make_float4(0.f, 0.f, 0.f, 0.f);
        bf16x8 a;
        a[0] = (short)f2bf(u0.x); a[1] = (short)f2bf(u0.y);
        a[2] = (short)f2bf(u0.z); a[3] = (short)f2bf(u0.w);
        a[4] = (short)f2bf(u1.x); a[5] = (short)f2bf(u1.y);
        a[6] = (short)f2bf(u1.z); a[7] = (short)f2bf(u1.w);
        afr[ks] = a;
    }

    // ---- MFMA main loop: 16 N-tiles x 4 K-steps ----
    f32x4 acc[16];
    #pragma unroll
    for (int ni = 0; ni < 16; ++ni) acc[ni] = (f32x4){0.f, 0.f, 0.f, 0.f};

    const int bco = (l & 15) * 256 + (l >> 4) * 16; // per-lane byte base
    const int bxo = (l & 7) << 4;                   // swizzle (c&7 == l&7)
    #pragma unroll
    for (int ks = 0; ks < 4; ++ks) {
        #pragma unroll
        for (int ni = 0; ni < 16; ++ni) {
            const int byte = ((ni * 16) * 256 + bco + ks * 64) ^ bxo;
            const bf16x8 b = *reinterpret_cast<const bf16x8*>(lbase + byte);
            acc[ni] = __builtin_amdgcn_mfma_f32_16x16x32_bf16(afr[ks], b, acc[ni], 0, 0, 0);
        }
    }

    // ---- attention logits from C fragments (h = first 8 N-tiles) ----
    // C layout: col = ni*16 + (l&15), row = row0 + (l>>4)*4 + q
    float ps[4][4], pd[4][4];
    #pragma unroll
    for (int h = 0; h < 4; ++h)
        #pragma unroll
        for (int q = 0; q < 4; ++q) { ps[h][q] = 0.f; pd[h][q] = 0.f; }

    #pragma unroll
    for (int ni = 0; ni < 8; ++ni) {
        const float as = att_src[ni * 16 + (l & 15)];
        const float ad = att_dst[ni * 16 + (l & 15)];
        #pragma unroll
        for (int q = 0; q < 4; ++q) {
            ps[ni >> 1][q] += acc[ni][q] * as;
            pd[ni >> 1][q] += acc[ni][q] * ad;
        }
    }
    #pragma unroll
    for (int h = 0; h < 4; ++h) {
        #pragma unroll
        for (int q = 0; q < 4; ++q) {
            float v = ps[h][q];
            v += __shfl_xor(v, 1); v += __shfl_xor(v, 2);
            v += __shfl_xor(v, 4); v += __shfl_xor(v, 8);
            ps[h][q] = v;
            float u = pd[h][q];
            u += __shfl_xor(u, 1); u += __shfl_xor(u, 2);
            u += __shfl_xor(u, 4); u += __shfl_xor(u, 8);
            pd[h][q] = u;
        }
    }
    if ((l & 15) == 0) {
        #pragma unroll
        for (int q = 0; q < 4; ++q) {
            const int row = row0 + (l >> 4) * 4 + q;
            if (row < n) {
                *reinterpret_cast<float4*>(a_src + (size_t)row * 4) =
                    make_float4(ps[0][q], ps[1][q], ps[2][q], ps[3][q]);
                *reinterpret_cast<float4*>(a_dst + (size_t)row * 4) =
                    make_float4(pd[0][q], pd[1][q], pd[2][q], pd[3][q]);
            }
        }
    }

    // ---- bf16 pack of all 256 cols ----
    #pragma unroll
    for (int ni = 0; ni < 16; ++ni) {
        #pragma unroll
        for (int q = 0; q < 4; ++q) {
            const int row = row0 + (l >> 4) * 4 + q;
            if (row < n)
                pk[(size_t)row * 256 + ni * 16 + (l & 15)] = f2bf(acc[ni][q]);
        }
    }
}

// K2a: per-256-chunk sums of counts
__global__ __launch_bounds__(256) void k_scan1(const int* __restrict__ counts,
                                               int* __restrict__ bsum, int n)
{
    __shared__ int sh[256];
    int t = threadIdx.x;
    int i = blockIdx.x * 256 + t;
    sh[t] = (i < n) ? counts[i] : 0;
    __syncthreads();
    #pragma unroll
    for (int off = 128; off >= 1; off >>= 1) {
        if (t < off) sh[t] += sh[t + off];
        __syncthreads();
    }
    if (t == 0) bsum[blockIdx.x] = sh[0];
}

// K2b: exclusive scan of block sums (nb <= 256), single block
__global__ __launch_bounds__(256) void k_scan2(int* __restrict__ bsum, int nb)
{
    __shared__ int sh[256];
    int t = threadIdx.x;
    int v = (t < nb) ? bsum[t] : 0;
    sh[t] = v;
    __syncthreads();
    #pragma unroll
    for (int off = 1; off < 256; off <<= 1) {
        int u = (t >= off) ? sh[t - off] : 0;
        __syncthreads();
        sh[t] += u;
        __syncthreads();
    }
    if (t < nb) bsum[t] = sh[t] - v;   // exclusive
}

// K2c: rowptr + cursor + dinv = rsqrt(1+deg)
__global__ __launch_bounds__(256) void k_scan3(
    const int* __restrict__ counts, const int* __restrict__ bsum,
    int* __restrict__ rowptr, int* __restrict__ cursor,
    float* __restrict__ dinv, int n)
{
    __shared__ int sh[256];
    int t = threadIdx.x;
    int i = blockIdx.x * 256 + t;
    int v = (i < n) ? counts[i] : 0;
    sh[t] = v;
    __syncthreads();
    #pragma unroll
    for (int off = 1; off < 256; off <<= 1) {
        int u = (t >= off) ? sh[t - off] : 0;
        __syncthreads();
        sh[t] += u;
        __syncthreads();
    }
    if (i < n) {
        int excl = bsum[blockIdx.x] + sh[t] - v;
        rowptr[i] = excl;
        cursor[i] = excl;
        dinv[i] = rsqrtf((float)(1 + v));
        if (i == n - 1) rowptr[n] = excl + v;
    }
}

// K3: scatter src indices into CSR order
__global__ void k_scatter(const int* __restrict__ src, const int* __restrict__ dst,
                          int* __restrict__ cursor, int* __restrict__ esorted, int E)
{
    int i = blockIdx.x * blockDim.x + threadIdx.x;
    if (i < E) {
        int p = atomicAdd(&cursor[dst[i]], 1);
        esorted[p] = src[i];
    }
}

// K4: single-pass gather (deferred softmax norm) + gate + residual + LN
// wave per node; lane owns channels {2l, 2l+1} -> single head per lane
__global__ __launch_bounds__(256) void k_fused(
    const int* __restrict__ esorted, const int* __restrict__ rowptr,
    const unsigned int* __restrict__ pku,       // pk as ushort2 pairs
    const float* __restrict__ a_src, const float* __restrict__ a_dst,
    const float* __restrict__ dinv, const float* __restrict__ x,
    const float* __restrict__ gat_bias, const float* __restrict__ gcn_bias,
    const float* __restrict__ gate_W, const float* __restrict__ gate_b,
    const float* __restrict__ gamma, const float* __restrict__ beta,
    float* __restrict__ out, int n)
{
    const int lane = threadIdx.x & 63;
    const int node = blockIdx.x * 4 + (threadIdx.x >> 6);
    if (node >= n) return;

    const int head = lane >> 4;                 // c=2l -> head = (2l)>>5 = l>>4
    const float adh = a_dst[node * 4 + head];
    const int beg = rowptr[node], end = rowptr[node + 1];

    float acc0 = 0.f, acc1 = 0.f, accg0 = 0.f, accg1 = 0.f, ws = 0.f;

#define EDGE_BODY(HU, GU, AV, DI)                                        \
    {                                                                    \
        float e = (AV) + adh; e = e > 0.f ? e : 0.2f * e;                \
        float w = __expf(e); ws += w;                                    \
        acc0  = fmaf(w, bflo(HU), acc0);                                 \
        acc1  = fmaf(w, bfhi(HU), acc1);                                 \
        accg0 = fmaf((DI), bflo(GU), accg0);                             \
        accg1 = fmaf((DI), bfhi(GU), accg1);                             \
    }

    int j = beg;
    for (; j + 4 <= end; j += 4) {
        const int s0 = esorted[j],     s1 = esorted[j + 1];
        const int s2 = esorted[j + 2], s3 = esorted[j + 3];
        const unsigned int h0 = pku[(size_t)s0 * 128 + lane];
        const unsigned int h1 = pku[(size_t)s1 * 128 + lane];
        const unsigned int h2 = pku[(size_t)s2 * 128 + lane];
        const unsigned int h3 = pku[(size_t)s3 * 128 + lane];
        const unsigned int g0 = pku[(size_t)s0 * 128 + 64 + lane];
        const unsigned int g1 = pku[(size_t)s1 * 128 + 64 + lane];
        const unsigned int g2 = pku[(size_t)s2 * 128 + 64 + lane];
        const unsigned int g3 = pku[(size_t)s3 * 128 + 64 + lane];
        const float a0 = a_src[s0 * 4 + head], a1 = a_src[s1 * 4 + head];
        const float a2 = a_src[s2 * 4 + head], a3 = a_src[s3 * 4 + head];
        const float d0 = dinv[s0], d1 = dinv[s1], d2 = dinv[s2], d3 = dinv[s3];
        EDGE_BODY(h0, g0, a0, d0);
        EDGE_BODY(h1, g1, a1, d1);
        EDGE_BODY(h2, g2, a2, d2);
        EDGE_BODY(h3, g3, a3, d3);
    }
    for (; j < end; ++j) {
        const int s = esorted[j];
        const unsigned int hu = pku[(size_t)s * 128 + lane];
        const unsigned int gu = pku[(size_t)s * 128 + 64 + lane];
        const float av = a_src[s * 4 + head];
        const float di = dinv[s];
        EDGE_BODY(hu, gu, av, di);
    }

    // self loop
    const float dvd = dinv[node];
    {
        const unsigned int hu = pku[(size_t)node * 128 + lane];
        const unsigned int gu = pku[(size_t)node * 128 + 64 + lane];
        const float av = a_src[node * 4 + head];
        EDGE_BODY(hu, gu, av, dvd);
    }
#undef EDGE_BODY

    // ---- epilogue: gate softmax + fuse + residual + LayerNorm ----
    const float2 gb2 = *reinterpret_cast<const float2*>(gat_bias + 2 * lane);
    const float2 gc2 = *reinterpret_cast<const float2*>(gcn_bias + 2 * lane);
    const float iws = 1.f / ws;
    float ga0 = acc0 * iws + gb2.x;
    float ga1 = acc1 * iws + gb2.y;
    float gc0 = accg0 * dvd + gc2.x;
    float gc1 = accg1 * dvd + gc2.y;

    const float4 gwa = *reinterpret_cast<const float4*>(gate_W + 4 * lane);
    const float4 gwb = *reinterpret_cast<const float4*>(gate_W + 256 + 4 * lane);
    float z0 = ga0 * gwa.x + ga1 * gwa.z + gc0 * gwb.x + gc1 * gwb.z;
    float z1 = ga0 * gwa.y + ga1 * gwa.w + gc0 * gwb.y + gc1 * gwb.w;
    #pragma unroll
    for (int off = 32; off >= 1; off >>= 1) {
        z0 += __shfl_xor(z0, off);
        z1 += __shfl_xor(z1, off);
    }
    z0 += gate_b[0]; z1 += gate_b[1];
    float m = fmaxf(z0, z1);
    float ez0 = __expf(z0 - m), ez1 = __expf(z1 - m);
    float inv = 1.f / (ez0 + ez1);
    float g0 = ez0 * inv, g1 = ez1 * inv;

    const size_t nbase = (size_t)node * 128;
    const float2 xv = *reinterpret_cast<const float2*>(x + nbase + 2 * lane);
    float y0 = g0 * ga0 + g1 * gc0 + xv.x;
    float y1 = g0 * ga1 + g1 * gc1 + xv.y;

    float sum = y0 + y1;
    #pragma unroll
    for (int off = 32; off >= 1; off >>= 1) sum += __shfl_xor(sum, off);
    float mu = sum * (1.f / 128.f);
    float d0v = y0 - mu, d1v = y1 - mu;
    float sq = d0v * d0v + d1v * d1v;
    #pragma unroll
    for (int off = 32; off >= 1; off >>= 1) sq += __shfl_xor(sq, off);
    float r = rsqrtf(sq * (1.f / 128.f) + 1e-5f);

    const float2 gm = *reinterpret_cast<const float2*>(gamma + 2 * lane);
    const float2 bt = *reinterpret_cast<const float2*>(beta + 2 * lane);
    float2 o;
    o.x = d0v * r * gm.x + bt.x;
    o.y = d1v * r * gm.y + bt.y;
    *reinterpret_cast<float2*>(out + nbase + 2 * lane) = o;
}

extern "C" void kernel_launch(void* const* d_in, const int* in_sizes, int n_in,
                              void* d_out, int out_size, void* d_ws, size_t ws_size,
                              hipStream_t stream)
{
    const float* x        = (const float*)d_in[0];
    const float* gat_W    = (const float*)d_in[1];
    const float* att_src  = (const float*)d_in[2];
    const float* att_dst  = (const float*)d_in[3];
    const float* gat_bias = (const float*)d_in[4];
    const float* gcn_W    = (const float*)d_in[5];
    const float* gcn_bias = (const float*)d_in[6];
    const float* gate_W   = (const float*)d_in[7];
    const float* gate_b   = (const float*)d_in[8];
    const float* ln_gamma = (const float*)d_in[9];
    const float* ln_beta  = (const float*)d_in[10];
    const int*   edge     = (const int*)d_in[11];

    const int n = in_sizes[0] / 128;
    const int E = in_sizes[11] / 2;
    const int* src = edge;
    const int* dst = edge + E;
    const int nb_chunks = (n + 255) / 256;   // 196 for n=50000 (<=256 required)

    char* w = (char*)d_ws;
    unsigned short* pk = (unsigned short*)w;  w += (size_t)n * 256 * 2;
    unsigned short* wt = (unsigned short*)w;  w += (size_t)256 * 128 * 2;
    float* a_src   = (float*)w;  w += (size_t)n * 4 * 4;
    float* a_dst   = (float*)w;  w += (size_t)n * 4 * 4;
    float* dinv    = (float*)w;  w += (size_t)n * 4;
    int*   counts  = (int*)w;    w += (size_t)n * 4;
    int*   bsum    = (int*)w;    w += (size_t)256 * 4;
    int*   rowptr  = (int*)w;    w += (size_t)(n + 1) * 4;
    int*   cursor  = (int*)w;    w += (size_t)n * 4;
    int*   esorted = (int*)w;    w += (size_t)E * 4;

    const int histBlocks = 512;
    const int gemmBlocks = (n + 63) / 64;    // 782

    k_prep<<<16, 256, 0, stream>>>(gat_W, gcn_W, wt, counts, n);
    k_combo<<<histBlocks + gemmBlocks, 256, 0, stream>>>(
        x, wt, att_src, att_dst, dst, counts, pk, a_src, a_dst, n, E, histBlocks);
    k_scan1<<<nb_chunks, 256, 0, stream>>>(counts, bsum, n);
    k_scan2<<<1, 256, 0, stream>>>(bsum, nb_chunks);
    k_scan3<<<nb_chunks, 256, 0, stream>>>(counts, bsum, rowptr, cursor, dinv, n);
    k_scatter<<<(E + 255) / 256, 256, 0, stream>>>(src, dst, cursor, esorted, E);
    k_fused<<<(n + 3) / 4, 256, 0, stream>>>(esorted, rowptr, (const unsigned int*)pk,
                                             a_src, a_dst, dinv, x, gat_bias, gcn_bias,
                                             gate_W, gate_b, ln_gamma, ln_beta,
                                             (float*)d_out, n);
}